// Round 13
// baseline (104.684 us; speedup 1.0000x reference)
//
#include <hip/hip_runtime.h>

#define S_TOT 4096
#define C_DIM 768
#define QKV_LD 2304
#define NH 12
// 1/sqrt(64) * log2(e), folded into Wq so softmax runs in exp2 domain
#define QSCALE 0.18033688011112042f

using f32x4  = __attribute__((ext_vector_type(4))) float;
using bf16x8 = __attribute__((ext_vector_type(8))) __bf16;

#if __has_builtin(__builtin_amdgcn_exp2f)
#define EXP2(x) __builtin_amdgcn_exp2f(x)
#else
#define EXP2(x) exp2f(x)
#endif

// Full drain + barrier (GEMM single-buffer publish; replay race seen in R5
// when relying on implicit drain).
#define DRAIN_AND_BARRIER()                                     \
  do {                                                          \
    asm volatile("s_waitcnt vmcnt(0) lgkmcnt(0)" ::: "memory"); \
    __builtin_amdgcn_sched_barrier(0);                          \
    __syncthreads();                                            \
  } while (0)

__device__ inline unsigned short f2bf_bits(float f) {
  unsigned int u = __float_as_uint(f);
  u = (u + 0x7FFFu + ((u >> 16) & 1u)) >> 16;
  return (unsigned short)u;
}
__device__ inline __bf16 f2bf(float f) {
  unsigned short s = f2bf_bits(f);
  __bf16 b;
  __builtin_memcpy(&b, &s, 2);
  return b;
}

// async global->LDS, 16B per lane; LDS dest = wave-uniform base + lane*16
__device__ __forceinline__ void gl_lds16(const __bf16* g, __bf16* l) {
  __builtin_amdgcn_global_load_lds(
      (__attribute__((address_space(1))) void*)(g),
      (__attribute__((address_space(3))) void*)(l), 16, 0, 0);
}

// One fused f32->bf16 cast for x, Wq(scaled), Wk, Wv, Wo into contiguous ws.
__global__ void cvt_all(const float* __restrict__ x, const float* __restrict__ Wq,
                        const float* __restrict__ Wk, const float* __restrict__ Wv,
                        const float* __restrict__ Wo, __bf16* __restrict__ dst) {
  const int XN = S_TOT * C_DIM;      // 3145728
  const int WN = C_DIM * C_DIM;      // 589824
  int i = (blockIdx.x * blockDim.x + threadIdx.x) * 4;
  if (i >= XN + 4 * WN) return;
  const float* src; float scale = 1.f; int off;
  if (i < XN)               { src = x;  off = i; }
  else if (i < XN + WN)     { src = Wq; off = i - XN; scale = QSCALE; }
  else if (i < XN + 2 * WN) { src = Wk; off = i - XN - WN; }
  else if (i < XN + 3 * WN) { src = Wv; off = i - XN - 2 * WN; }
  else                      { src = Wo; off = i - XN - 3 * WN; }
  float4 v = *reinterpret_cast<const float4*>(src + off);
  ushort4 o;
  o.x = f2bf_bits(v.x * scale); o.y = f2bf_bits(v.y * scale);
  o.z = f2bf_bits(v.z * scale); o.w = f2bf_bits(v.w * scale);
  *reinterpret_cast<ushort4*>(reinterpret_cast<unsigned short*>(dst) + i) = o;
}

// C = A @ B^T, 128x128 tile, BK=64, 4 waves (2x2, each 64x64 = 4x4 frags).
// global_load_lds 16B staging, single-buffer 2-barrier K-loop, 16B-chunk XOR
// swizzle. SPLIT_V: n-tiles >=1536 (V projection) written straight from
// registers into V2[h][tile64][chunk8][d64] (8-key chunks of the pi-permuted
// seq order) so attention PV fragments are coalesced 16B global loads.
template<bool OUT_BIAS_F32, bool SPLIT_V>
__global__ __launch_bounds__(256) void gemm128(
    const __bf16* __restrict__ A, const __bf16* __restrict__ B,
    void* __restrict__ Cv, const float* __restrict__ bias,
    __bf16* __restrict__ V2, int K, int ldc) {
  __shared__ __bf16 As[128][64];
  __shared__ __bf16 Bs[128][64];
  const int t = threadIdx.x, lane = t & 63, wv = t >> 6;
  const int wr = wv >> 1, wc = wv & 1;
  const int lhi = lane >> 4, llo = lane & 15;
  const int m0 = blockIdx.y * 128, n0 = blockIdx.x * 128;

  f32x4 acc[4][4];
  #pragma unroll
  for (int a = 0; a < 4; ++a)
    #pragma unroll
    for (int b = 0; b < 4; ++b) acc[a][b] = (f32x4){0.f, 0.f, 0.f, 0.f};

  for (int kt = 0; kt < K; kt += 64) {
    __syncthreads();                       // previous tile fully consumed
    #pragma unroll
    for (int n = 0; n < 4; ++n) {
      const int ci = n * 256 + wv * 64 + lane;   // 16B-chunk id 0..1023
      const int r = ci >> 3;                     // tile row 0..127
      const int cc = (ci & 7) ^ (r & 7);         // inverse-swizzled src chunk
      gl_lds16(A + (size_t)(m0 + r) * K + kt + cc * 8, &As[0][0] + ci * 8);
      gl_lds16(B + (size_t)(n0 + r) * K + kt + cc * 8, &Bs[0][0] + ci * 8);
    }
    DRAIN_AND_BARRIER();
    #pragma unroll
    for (int kk = 0; kk < 2; ++kk) {
      bf16x8 af[4], bfr[4];
      #pragma unroll
      for (int mi = 0; mi < 4; ++mi) {
        const int row = wr * 64 + mi * 16 + llo;
        af[mi] = *reinterpret_cast<const bf16x8*>(
            &As[0][0] + row * 64 + (((kk << 2) | lhi) ^ (llo & 7)) * 8);
      }
      #pragma unroll
      for (int ni = 0; ni < 4; ++ni) {
        const int row = wc * 64 + ni * 16 + llo;
        bfr[ni] = *reinterpret_cast<const bf16x8*>(
            &Bs[0][0] + row * 64 + (((kk << 2) | lhi) ^ (llo & 7)) * 8);
      }
      #pragma unroll
      for (int mi = 0; mi < 4; ++mi)
        #pragma unroll
        for (int ni = 0; ni < 4; ++ni)
          acc[mi][ni] = __builtin_amdgcn_mfma_f32_16x16x32_bf16(af[mi], bfr[ni], acc[mi][ni], 0, 0, 0);
    }
  }

  if (SPLIT_V && n0 >= 1536) {
    // V projection -> V2[h][T][c][d] (16B per (c,d), pi-permuted seq).
    const int head = (n0 - 1536 + wc * 64) >> 6;       // uniform per wave
    const int T = (m0 >> 6) + wr;
    #pragma unroll
    for (int mi = 0; mi < 4; ++mi) {
      const int c = (mi >> 1) * 4 + lhi;
      #pragma unroll
      for (int ni = 0; ni < 4; ++ni) {
        const int d = ni * 16 + llo;
        ushort4 o;
        o.x = f2bf_bits(acc[mi][ni][0]); o.y = f2bf_bits(acc[mi][ni][1]);
        o.z = f2bf_bits(acc[mi][ni][2]); o.w = f2bf_bits(acc[mi][ni][3]);
        uint2 u; __builtin_memcpy(&u, &o, 8);
        *reinterpret_cast<uint2*>(
            V2 + ((((size_t)head * 64 + T) * 8 + c) * 64 + d) * 8 + (mi & 1) * 4) = u;
      }
    }
    return;
  }

  #pragma unroll
  for (int mi = 0; mi < 4; ++mi)
    #pragma unroll
    for (int ni = 0; ni < 4; ++ni)
      #pragma unroll
      for (int i = 0; i < 4; ++i) {
        const int row = m0 + wr * 64 + mi * 16 + lhi * 4 + i;
        const int col = n0 + wc * 64 + ni * 16 + llo;
        if constexpr (OUT_BIAS_F32) {
          reinterpret_cast<float*>(Cv)[(size_t)row * ldc + col] = acc[mi][ni][i] + bias[col];
        } else {
          reinterpret_cast<__bf16*>(Cv)[(size_t)row * ldc + col] = f2bf(acc[mi][ni][i]);
        }
      }
}

// v12 decode: 960 blocks, 128 q-rows each, 12-16 tiles/block, heavy-first.
// qb = qb128 (0..31), vq = qb>>2. slot = -1 -> direct att write.
// A qb28-31: 4x16 | C qb20-23: 3x16 | E qb12-15: 2x16 | G qb0-7: 1x16 direct
// B qb24-27: 4x14 | D qb16-19: (14,13,13) | F qb8-11: 2x12
__device__ __forceinline__ void decode12(int j, int& qb, int& h, int& nt,
                                         int& kstart, int& slot) {
  if (j < 192) {            // A
    const int c = j & 3, u = j >> 2;
    qb = 28 + (u & 3); h = u >> 2; nt = 16; kstart = c * 1024;
    slot = ((u & 3) * 12 + h) * 4 + c;
  } else if (j < 336) {     // C
    const int k = j - 192, c = k % 3, u = k / 3;
    qb = 20 + (u & 3); h = u >> 2; nt = 16; kstart = c * 1024;
    slot = 384 + ((u & 3) * 12 + h) * 3 + c;
  } else if (j < 432) {     // E
    const int k = j - 336, c = k & 1, u = k >> 1;
    qb = 12 + (u & 3); h = u >> 2; nt = 16; kstart = c * 1024;
    slot = 672 + ((u & 3) * 12 + h) * 2 + c;
  } else if (j < 528) {     // G (direct)
    const int k = j - 432;
    qb = k & 7; h = k >> 3; nt = 16; kstart = 0; slot = -1;
  } else if (j < 720) {     // B
    const int k = j - 528, c = k & 3, u = k >> 2;
    qb = 24 + (u & 3); h = u >> 2; nt = 14; kstart = c * 896;
    slot = 192 + ((u & 3) * 12 + h) * 4 + c;
  } else if (j < 864) {     // D
    const int k = j - 720, c = k % 3, u = k / 3;
    qb = 16 + (u & 3); h = u >> 2; nt = (c == 0) ? 14 : 13;
    kstart = (c == 0) ? 0 : (896 + (c - 1) * 832);
    slot = 528 + ((u & 3) * 12 + h) * 3 + c;
  } else {                  // F
    const int k = j - 864, c = k & 1, u = k >> 1;
    qb = 8 + (u & 3); h = u >> 2; nt = 12; kstart = c * 768;
    slot = 768 + ((u & 3) * 12 + h) * 2 + c;
  }
}

// Flash attention v12: each wave owns 32 q-rows (two 16-row groups) sharing
// the K LDS reads and the V register fragments -> 32 MFMA per wave-tile for
// the same fixed per-tile cost (barrier, waits, 8 K-reads, 8 V-loads).
// Triple-buffered K LDS (24 KB), per-tile counted vmcnt(2). Max-free exp2.
__global__ __launch_bounds__(256) void attn_fused12(
    const __bf16* __restrict__ QKV, const __bf16* __restrict__ V2,
    __bf16* __restrict__ att, float* __restrict__ Opart,
    float* __restrict__ lpart) {
  __shared__ __bf16 Ks[3][64][64];
  const int t = threadIdx.x, lane = t & 63, wv = t >> 6;
  const int llo = lane & 15, hi = lane >> 4;
  const int sw = llo & 7;
  int qb, h, n_tiles, kstart, slot;
  decode12((int)blockIdx.x, qb, h, n_tiles, kstart, slot);
  const int q0 = qb * 128 + wv * 32;    // wave's 32 rows: q0 + g*16 + llo

  bf16x8 qf[2][2];
  #pragma unroll
  for (int g = 0; g < 2; ++g) {
    const __bf16* qrow = QKV + (size_t)(q0 + g * 16 + llo) * QKV_LD + h * 64;
    qf[g][0] = *reinterpret_cast<const bf16x8*>(qrow + hi * 8);
    qf[g][1] = *reinterpret_cast<const bf16x8*>(qrow + 32 + hi * 8);
  }
  asm volatile("s_waitcnt vmcnt(0)" ::: "memory");

  f32x4 Oa[2][4];
  #pragma unroll
  for (int g = 0; g < 2; ++g)
    #pragma unroll
    for (int dt = 0; dt < 4; ++dt) Oa[g][dt] = (f32x4){0.f, 0.f, 0.f, 0.f};
  float l0 = 0.f, l1 = 0.f;

  // K staging pointers: two 16B chunks per lane per tile, fixed strides.
  const int ci0 = (wv * 2 + 0) * 64 + lane, r0 = ci0 >> 3, c0 = (ci0 & 7) ^ (r0 & 7);
  const int ci1 = (wv * 2 + 1) * 64 + lane, r1 = ci1 >> 3, c1 = (ci1 & 7) ^ (r1 & 7);
  const __bf16* kp0 = QKV + (size_t)(kstart + r0) * QKV_LD + C_DIM + h * 64 + c0 * 8;
  const __bf16* kp1 = QKV + (size_t)(kstart + r1) * QKV_LD + C_DIM + h * 64 + c1 * 8;
  __bf16* const kd0 = &Ks[0][0][0] + (wv * 2 + 0) * 512;
  __bf16* const kd1 = &Ks[0][0][0] + (wv * 2 + 1) * 512;

  auto stage = [&](int buf) {
    const size_t bo = (size_t)buf * 4096;
    gl_lds16(kp0, kd0 + bo);
    gl_lds16(kp1, kd1 + bo);
    kp0 += (size_t)64 * QKV_LD; kp1 += (size_t)64 * QKV_LD;
  };

  // V fragment base: frag(dt,mm) at vg + mm*2048 + dt*128 (+4096 per tile).
  const __bf16* vg = V2 + ((size_t)(h * 64 + (kstart >> 6))) * 4096 + hi * 512 + llo * 8;

  // softmax + PV for one q-group (all compile-time indexed)
  auto soft_pv = [&](f32x4 (&sc)[4], float& l, f32x4 (&Og)[4], bf16x8 (&va)[4][2]) {
    float pp[4][4];
    #pragma unroll
    for (int nt = 0; nt < 4; ++nt)
      #pragma unroll
      for (int i = 0; i < 4; ++i) pp[nt][i] = EXP2(sc[nt][i]);
    float t0 = (pp[0][0] + pp[0][1]) + (pp[0][2] + pp[0][3]);
    float t1 = (pp[1][0] + pp[1][1]) + (pp[1][2] + pp[1][3]);
    float t2 = (pp[2][0] + pp[2][1]) + (pp[2][2] + pp[2][3]);
    float t3 = (pp[3][0] + pp[3][1]) + (pp[3][2] + pp[3][3]);
    l += (t0 + t1) + (t2 + t3);
    bf16x8 pf[2];
    #pragma unroll
    for (int mm = 0; mm < 2; ++mm)
      #pragma unroll
      for (int jj = 0; jj < 8; ++jj)
        pf[mm][jj] = (__bf16)pp[2 * mm + (jj >> 2)][jj & 3];
    #pragma unroll
    for (int dt = 0; dt < 4; ++dt)
      #pragma unroll
      for (int mm = 0; mm < 2; ++mm)
        Og[dt] = __builtin_amdgcn_mfma_f32_16x16x32_bf16(va[dt][mm], pf[mm], Og[dt], 0, 0, 0);
  };

  stage(0);
  stage(1);
  int cur = 0;
  for (int tt = 0; tt < n_tiles; ++tt) {
    if (tt + 1 < n_tiles) {
      asm volatile("s_waitcnt vmcnt(2)" ::: "memory");
    } else {
      asm volatile("s_waitcnt vmcnt(0)" ::: "memory");
    }
    __builtin_amdgcn_sched_barrier(0);
    __builtin_amdgcn_s_barrier();
    __builtin_amdgcn_sched_barrier(0);

    // V fragments (shared by both q-groups); issued first so the K stage
    // below stays youngest in the vmem queue
    bf16x8 va[4][2];
    #pragma unroll
    for (int dt = 0; dt < 4; ++dt)
      #pragma unroll
      for (int mm = 0; mm < 2; ++mm)
        va[dt][mm] = *reinterpret_cast<const bf16x8*>(vg + mm * 2048 + dt * 128);
    __builtin_amdgcn_sched_barrier(0);

    if (tt + 2 < n_tiles) {
      const int nxt = (cur + 2 >= 3) ? cur - 1 : cur + 2;
      stage(nxt);
    }
    const __bf16* Kb = &Ks[cur][0][0];

    // ---- QK^T both groups, shared K fragment reads: 16 mfma
    f32x4 sc[2][4];
    #pragma unroll
    for (int g = 0; g < 2; ++g)
      #pragma unroll
      for (int nt = 0; nt < 4; ++nt) sc[g][nt] = (f32x4){0.f, 0.f, 0.f, 0.f};
    #pragma unroll
    for (int nt = 0; nt < 4; ++nt) {
      const __bf16* kr = Kb + (nt * 16 + llo) * 64;
      bf16x8 kf0 = *reinterpret_cast<const bf16x8*>(kr + ((hi ^ sw) * 8));
      bf16x8 kf1 = *reinterpret_cast<const bf16x8*>(kr + (((4 + hi) ^ sw) * 8));
      sc[0][nt] = __builtin_amdgcn_mfma_f32_16x16x32_bf16(kf0, qf[0][0], sc[0][nt], 0, 0, 0);
      sc[0][nt] = __builtin_amdgcn_mfma_f32_16x16x32_bf16(kf1, qf[0][1], sc[0][nt], 0, 0, 0);
      sc[1][nt] = __builtin_amdgcn_mfma_f32_16x16x32_bf16(kf0, qf[1][0], sc[1][nt], 0, 0, 0);
      sc[1][nt] = __builtin_amdgcn_mfma_f32_16x16x32_bf16(kf1, qf[1][1], sc[1][nt], 0, 0, 0);
    }

    // ---- softmax + PV per group (V frags reused): 16 mfma + 32 exp2
    soft_pv(sc[0], l0, Oa[0], va);
    soft_pv(sc[1], l1, Oa[1], va);

    vg += 4096;
    cur = (cur + 1 == 3) ? 0 : cur + 1;
  }

  // ---- epilogue (per group)
  l0 += __shfl_xor(l0, 16); l0 += __shfl_xor(l0, 32);
  l1 += __shfl_xor(l1, 16); l1 += __shfl_xor(l1, 32);
  if (slot < 0) {
    #pragma unroll
    for (int g = 0; g < 2; ++g) {
      const float inv = 1.f / (g == 0 ? l0 : l1);
      const int row = q0 + g * 16 + llo;
      #pragma unroll
      for (int dt = 0; dt < 4; ++dt) {
        ushort4 o;
        o.x = f2bf_bits(Oa[g][dt][0] * inv);
        o.y = f2bf_bits(Oa[g][dt][1] * inv);
        o.z = f2bf_bits(Oa[g][dt][2] * inv);
        o.w = f2bf_bits(Oa[g][dt][3] * inv);
        *reinterpret_cast<ushort4*>(att + (size_t)row * C_DIM + h * 64 + dt * 16 + hi * 4) = o;
      }
    }
  } else {
    #pragma unroll
    for (int g = 0; g < 2; ++g) {
      const int rloc = wv * 32 + g * 16 + llo;
      float* Ob = Opart + ((size_t)slot * 128 + rloc) * 64;
      #pragma unroll
      for (int dt = 0; dt < 4; ++dt)
        *reinterpret_cast<f32x4*>(Ob + dt * 16 + hi * 4) = Oa[g][dt];
      if (hi == 0) lpart[slot * 128 + rloc] = (g == 0 ? l0 : l1);
    }
  }
}

// Merge 2-4 kv-chunk partials for qb128 8..31: att = sum(O)/sum(l).
__global__ __launch_bounds__(512) void merge12(
    const float* __restrict__ Opart, const float* __restrict__ lpart,
    __bf16* __restrict__ att) {
  const int b = blockIdx.x;            // 0..287 = (qb-8)*12 + h
  const int qi = b / 12, h = b - qi * 12;
  const int qb = 8 + qi;
  int base, n;
  if      (qb >= 28) { n = 4; base = ((qb - 28) * 12 + h) * 4; }
  else if (qb >= 24) { n = 4; base = 192 + ((qb - 24) * 12 + h) * 4; }
  else if (qb >= 20) { n = 3; base = 384 + ((qb - 20) * 12 + h) * 3; }
  else if (qb >= 16) { n = 3; base = 528 + ((qb - 16) * 12 + h) * 3; }
  else if (qb >= 12) { n = 2; base = 672 + ((qb - 12) * 12 + h) * 2; }
  else               { n = 2; base = 768 + ((qb - 8) * 12 + h) * 2; }
  const int t = threadIdx.x;
  const int r = t >> 2, d0 = (t & 3) * 16;   // r 0..127
  f32x4 s[4] = {{0.f,0.f,0.f,0.f},{0.f,0.f,0.f,0.f},{0.f,0.f,0.f,0.f},{0.f,0.f,0.f,0.f}};
  float L = 0.f;
  for (int k = 0; k < n; ++k) {
    const float* O = Opart + ((size_t)(base + k) * 128 + r) * 64 + d0;
    #pragma unroll
    for (int i = 0; i < 4; ++i) {
      f32x4 v = *reinterpret_cast<const f32x4*>(O + i * 4);
      s[i][0] += v[0]; s[i][1] += v[1]; s[i][2] += v[2]; s[i][3] += v[3];
    }
    L += lpart[(base + k) * 128 + r];
  }
  const float linv = 1.f / L;
  __bf16* dst = att + ((size_t)qb * 128 + r) * C_DIM + h * 64 + d0;
  #pragma unroll
  for (int i = 0; i < 4; ++i) {
    ushort4 o;
    o.x = f2bf_bits(s[i][0] * linv);
    o.y = f2bf_bits(s[i][1] * linv);
    o.z = f2bf_bits(s[i][2] * linv);
    o.w = f2bf_bits(s[i][3] * linv);
    *reinterpret_cast<ushort4*>(dst + i * 4) = o;
  }
}

extern "C" void kernel_launch(void* const* d_in, const int* in_sizes, int n_in,
                              void* d_out, int out_size, void* d_ws, size_t ws_size,
                              hipStream_t stream) {
  const float* x  = (const float*)d_in[0];
  const float* Wq = (const float*)d_in[1];
  const float* Wk = (const float*)d_in[2];
  const float* Wv = (const float*)d_in[3];
  const float* Wo = (const float*)d_in[4];
  const float* bo = (const float*)d_in[5];

  __bf16* xb   = (__bf16*)d_ws;                          // [4096][768]
  __bf16* Wqkv = xb + (size_t)S_TOT * C_DIM;             // [2304][768]
  __bf16* Wob  = Wqkv + (size_t)3 * C_DIM * C_DIM;       // [768][768]
  __bf16* QKV  = Wob + (size_t)C_DIM * C_DIM;            // [4096][2304] (V region unused)
  __bf16* V2   = QKV + (size_t)S_TOT * QKV_LD;           // [12][64][8][64][8]
  __bf16* att  = V2 + (size_t)NH * 64 * S_TOT;           // [4096][768]
  float*  Opart = (float*)(att + (size_t)S_TOT * C_DIM); // [864][128][64] f32
  float*  lpart = Opart + (size_t)864 * 128 * 64;        // [864][128] f32

  // fused cast of all five f32 inputs (x, Wq*QSCALE, Wk, Wv, Wo)
  {
    const int tot = S_TOT * C_DIM + 4 * C_DIM * C_DIM;   // 5,505,024
    cvt_all<<<dim3((tot / 4 + 255) / 256), dim3(256), 0, stream>>>(
        x, Wq, Wk, Wv, Wo, xb);
  }

  // QKV projection (128^2 tiles); V tiles land in chunked-transposed V2
  gemm128<false, true><<<dim3(QKV_LD / 128, S_TOT / 128), dim3(256), 0, stream>>>(
      xb, Wqkv, (void*)QKV, nullptr, V2, C_DIM, QKV_LD);

  // flash attention (32 q-rows/wave, kv-split) -> att rows 0..1023 + partials
  attn_fused12<<<dim3(960), dim3(256), 0, stream>>>(QKV, V2, att, Opart, lpart);

  // merge kv-chunks -> att rows 1024..4095
  merge12<<<dim3(288), dim3(512), 0, stream>>>(Opart, lpart, att);

  // out = att @ Wo^T + bo : f32
  gemm128<true, false><<<dim3(C_DIM / 128, S_TOT / 128), dim3(256), 0, stream>>>(
      att, Wob, d_out, bo, nullptr, C_DIM, C_DIM);
}